// Round 11
// baseline (71.103 us; speedup 1.0000x reference)
//
#include <hip/hip_runtime.h>

typedef __bf16 bf16_t;
typedef __bf16 bf16x2 __attribute__((ext_vector_type(2)));
typedef __bf16 bf16x4 __attribute__((ext_vector_type(4)));
typedef __bf16 bf16x8 __attribute__((ext_vector_type(8)));
typedef float  f32x4  __attribute__((ext_vector_type(4)));
typedef float  f32x4u __attribute__((ext_vector_type(4), aligned(4)));
typedef short  s16x4  __attribute__((ext_vector_type(4)));
typedef unsigned int u32;

#define MFMA32(a, b, c) __builtin_amdgcn_mfma_f32_16x16x32_bf16((a), (b), (c), 0, 0, 0)

// K=16 MFMA: v_mfma_f32_16x16x16_bf16. Fragment maps (verified r10, passed):
//   A: lane holds A[c0][4g+i], B: lane holds B[4g+i][c0], D: reg r -> D[4g+r][c0].
// IDENTITY: a 16x16 D-tile is register-identical to a K=16 B-frag (r<->i) and to a
// K=16 A-frag of the transposed matrix -> Q/K/V/P D-layouts feed QK^T / PV with
// ZERO cross-lane ops.
union B4u { bf16x4 h; s16x4 s; };
__device__ __forceinline__ f32x4 MFMA16(bf16x4 a, bf16x4 b, f32x4 c) {
#if __has_builtin(__builtin_amdgcn_mfma_f32_16x16x16_bf16)
    return __builtin_amdgcn_mfma_f32_16x16x16_bf16(a, b, c, 0, 0, 0);
#elif __has_builtin(__builtin_amdgcn_mfma_f32_16x16x16bf16_1k)
    B4u ua, ub; ua.h = a; ub.h = b;
    return __builtin_amdgcn_mfma_f32_16x16x16bf16_1k(ua.s, ub.s, c, 0, 0, 0);
#else
    f32x4 d = c;
    asm volatile("v_mfma_f32_16x16x16_bf16 %0, %1, %2, %0"
                 : "+v"(d) : "v"(a), "v"(b));
    return d;
#endif
}

#define ROWB 272   // LDS tile row stride (natural +16B/row stagger -> 2-way, free)
#define TILEB 17408

__device__ __forceinline__ void st4(char* base, int row, int byteoff, bf16x4 v) {
    *(bf16x4*)(base + row * ROWB + byteoff) = v;
}
__device__ __forceinline__ bf16x8 ld8(const char* base, int row, int byteoff) {
    return *(const bf16x8*)(base + row * ROWB + byteoff);
}
__device__ __forceinline__ void stx(char* buf, int i, float4 f) {
    bf16x4 hq;
    hq[0] = (bf16_t)f.x; hq[1] = (bf16_t)f.y; hq[2] = (bf16_t)f.z; hq[3] = (bf16_t)f.w;
    st4(buf, i >> 5, (i & 31) << 3, hq);
}

__device__ __forceinline__ bf16x4 cvt4b(f32x4 v, float4 bias, float sc) {
    bf16x4 t;
    t[0] = (bf16_t)((v[0] + bias.x) * sc);
    t[1] = (bf16_t)((v[1] + bias.y) * sc);
    t[2] = (bf16_t)((v[2] + bias.z) * sc);
    t[3] = (bf16_t)((v[3] + bias.w) * sc);
    return t;
}
__device__ __forceinline__ bf16x4 cvt4s(f32x4 v, float bias) {
    bf16x4 t;
    t[0] = (bf16_t)(v[0] + bias);
    t[1] = (bf16_t)(v[1] + bias);
    t[2] = (bf16_t)(v[2] + bias);
    t[3] = (bf16_t)(v[3] + bias);
    return t;
}

__global__ void wconv_kernel(const float* __restrict__ qw, const float* __restrict__ pw,
                             bf16_t* __restrict__ o) {
    int i = (blockIdx.x * 256 + threadIdx.x) * 4;   // 64*256*4 = 65536
    const float* src = (i < 49152) ? (qw + i) : (pw + (i - 49152));
    float4 f = *(const float4*)src;
    bf16x4 h;
    h[0] = (bf16_t)f.x; h[1] = (bf16_t)f.y; h[2] = (bf16_t)f.z; h[3] = (bf16_t)f.w;
    *(bf16x4*)(o + i) = h;
}

template<int USEB>
__device__ __forceinline__ bf16x8 ldw(const float* __restrict__ wf,
                                      const bf16_t* __restrict__ wb, int idx) {
    if constexpr (USEB) {
        return *(const bf16x8*)(wb + idx);
    } else {
        float4 f0 = *(const float4*)(wf + idx);
        float4 f1 = *(const float4*)(wf + idx + 4);
        bf16x8 r;
        r[0] = (bf16_t)f0.x; r[1] = (bf16_t)f0.y; r[2] = (bf16_t)f0.z; r[3] = (bf16_t)f0.w;
        r[4] = (bf16_t)f1.x; r[5] = (bf16_t)f1.y; r[6] = (bf16_t)f1.z; r[7] = (bf16_t)f1.w;
        return r;
    }
}

// Fragment conventions for v_mfma_f32_16x16x32_bf16, D = A*B (verified r0-r10):
//  A (MxK): lane holds A[c0][8g+i], i=0..7
//  B (KxN): lane holds B[8g+i][c0]
//  D (MxN): lane reg r holds D[4g+r][c0]

// 512 threads = 8 waves = 2 windows x 4 heads. Per-wave code identical to r10
// (verified); window selected by wave>>2. Raises resident waves/CU (r3 vs r10
// evidence: resident BLOCKS/CU is ~1.5-3 regardless of size, so bigger blocks
// -> more waves resident).
template<int USEB>
__global__ __launch_bounds__(512, 2) void winattn_kernel(
    const float* __restrict__ xg, const float* __restrict__ maskg,
    const float* __restrict__ qwg, const float* __restrict__ qbg,
    const float* __restrict__ pwg, const float* __restrict__ pbg,
    const bf16_t* __restrict__ wqb, const bf16_t* __restrict__ wpb,
    const int nW, const int Btot, float* __restrict__ outg)
{
    __shared__ char xs2[2 * TILEB];   // per window: x [64][136] bf16, later att

    const int tid  = threadIdx.x;
    const int w8   = tid >> 6;        // 0..7
    const int win  = w8 >> 2;         // window within block
    const int h    = w8 & 3;          // head
    const int lane = tid & 63;
    const int g    = lane >> 4;
    const int c0   = lane & 15;

    const long b     = (long)blockIdx.x * 2 + win;
    const bool active = (b < Btot);
    char* xs = xs2 + win * TILEB;
    const int tid2 = tid & 255;       // within-window thread id (staging)

    // ---- stage x (49x128 f32 -> bf16 LDS); zero rows 49..63 ----
    if (active) {
        const float4* xb = (const float4*)(xg + b * 6272);
        #pragma unroll
        for (int it = 0; it < 7; ++it) {
            int i = tid2 + it * 256;
            if (i < 1568) { float4 f = xb[i]; stx(xs, i, f); }
        }
        #pragma unroll
        for (int it = 0; it < 4; ++it) {
            int i = tid2 + it * 256;
            if (i < 960) {
                int row = 49 + (i >> 6), byteo = (i & 63) << 2;
                *(u32*)(xs + row * ROWB + byteo) = 0u;
            }
        }
    }
    __syncthreads();   // b1: x staged (both windows)

    const float qs = 0.17677669529663687f;   // 32^-0.5

    bf16x4 qfr[2][4];    // [dt][qt]: q(tok=16qt+c0, ch=32h+16dt+4g+r)   K=16 B-frag
    bf16x4 kfr[4][2];    // [kt][dt]: k(tok=16kt+c0, ch=32h+16dt+4g+i)   K=16 A-frag
    bf16x4 vfr[2][4];    // [dt][kt]: v(tok=16kt+4g+i, ch=32h+16dt+c0)   K=16 A-frag

    if (active) {
        // ---- Q pass: D[dh][tok] = Wq * x^T ----
        {
            f32x4 acc[2][4];
            #pragma unroll
            for (int d = 0; d < 2; ++d)
                #pragma unroll
                for (int mt = 0; mt < 4; ++mt) acc[d][mt] = {0.f, 0.f, 0.f, 0.f};
            #pragma unroll
            for (int ks = 0; ks < 4; ++ks) {
                bf16x8 w0 = ldw<USEB>(qwg, wqb, (32*h + c0) * 128 + 32*ks + 8*g);
                bf16x8 w1 = ldw<USEB>(qwg, wqb, (32*h + 16 + c0) * 128 + 32*ks + 8*g);
                #pragma unroll
                for (int mt = 0; mt < 4; ++mt) {
                    bf16x8 xf = ld8(xs, 16*mt + c0, (32*ks + 8*g) * 2);
                    acc[0][mt] = MFMA32(w0, xf, acc[0][mt]);
                    acc[1][mt] = MFMA32(w1, xf, acc[1][mt]);
                }
            }
            float4 b0 = *(const float4*)(qbg + 32*h + 4*g);
            float4 b1 = *(const float4*)(qbg + 32*h + 16 + 4*g);
            #pragma unroll
            for (int qt = 0; qt < 4; ++qt) {
                qfr[0][qt] = cvt4b(acc[0][qt], b0, qs);
                qfr[1][qt] = cvt4b(acc[1][qt], b1, qs);
            }
        }
        // ---- K pass: D[dh][tok] = Wk * x^T ----
        {
            f32x4 acc[2][4];
            #pragma unroll
            for (int d = 0; d < 2; ++d)
                #pragma unroll
                for (int mt = 0; mt < 4; ++mt) acc[d][mt] = {0.f, 0.f, 0.f, 0.f};
            #pragma unroll
            for (int ks = 0; ks < 4; ++ks) {
                bf16x8 w0 = ldw<USEB>(qwg, wqb, (128 + 32*h + c0) * 128 + 32*ks + 8*g);
                bf16x8 w1 = ldw<USEB>(qwg, wqb, (128 + 32*h + 16 + c0) * 128 + 32*ks + 8*g);
                #pragma unroll
                for (int mt = 0; mt < 4; ++mt) {
                    bf16x8 xf = ld8(xs, 16*mt + c0, (32*ks + 8*g) * 2);
                    acc[0][mt] = MFMA32(w0, xf, acc[0][mt]);
                    acc[1][mt] = MFMA32(w1, xf, acc[1][mt]);
                }
            }
            float4 b0 = *(const float4*)(qbg + 128 + 32*h + 4*g);
            float4 b1 = *(const float4*)(qbg + 128 + 32*h + 16 + 4*g);
            #pragma unroll
            for (int kt = 0; kt < 4; ++kt) {
                kfr[kt][0] = cvt4b(acc[0][kt], b0, 1.f);
                kfr[kt][1] = cvt4b(acc[1][kt], b1, 1.f);
            }
        }
        // ---- V pass: D[tok][dh] = x * Wv^T ----
        {
            f32x4 acc[4][2];
            #pragma unroll
            for (int mt = 0; mt < 4; ++mt)
                #pragma unroll
                for (int d = 0; d < 2; ++d) acc[mt][d] = {0.f, 0.f, 0.f, 0.f};
            #pragma unroll
            for (int ks = 0; ks < 4; ++ks) {
                bf16x8 w0 = ldw<USEB>(qwg, wqb, (256 + 32*h + c0) * 128 + 32*ks + 8*g);
                bf16x8 w1 = ldw<USEB>(qwg, wqb, (256 + 32*h + 16 + c0) * 128 + 32*ks + 8*g);
                #pragma unroll
                for (int mt = 0; mt < 4; ++mt) {
                    bf16x8 xf = ld8(xs, 16*mt + c0, (32*ks + 8*g) * 2);
                    acc[mt][0] = MFMA32(xf, w0, acc[mt][0]);
                    acc[mt][1] = MFMA32(xf, w1, acc[mt][1]);
                }
            }
            float vb0 = qbg[256 + 32*h + c0];
            float vb1 = qbg[256 + 32*h + 16 + c0];
            #pragma unroll
            for (int kt = 0; kt < 4; ++kt) {
                vfr[0][kt] = cvt4s(acc[kt][0], vb0);
                vfr[1][kt] = cvt4s(acc[kt][1], vb1);
            }
        }
    }
    __syncthreads();   // b2: all x reads done -> att may overwrite region

    if (active) {
        // ---- attention per 16-q-tile: all operands in registers, zero shuffles ----
        const float* mrow = maskg + (long)(b % nW) * 2401;
        #pragma unroll
        for (int qt = 0; qt < 4; ++qt) {
            f32x4 s[4];
            #pragma unroll
            for (int kt = 0; kt < 4; ++kt) s[kt] = {0.f, 0.f, 0.f, 0.f};
            #pragma unroll
            for (int kt = 0; kt < 4; ++kt) {
                s[kt] = MFMA16(kfr[kt][0], qfr[0][qt], s[kt]);
                s[kt] = MFMA16(kfr[kt][1], qfr[1][qt], s[kt]);
            }
            // s[kt] reg r: kv=16kt+4g+r, q=16qt+c0

            {
                int q  = 16*qt + c0;
                int qm = q < 49 ? q : 48;
                const float* mr = mrow + qm * 49;
                f32x4u m0 = *(const f32x4u*)(mr + 4*g);
                f32x4u m1 = *(const f32x4u*)(mr + 16 + 4*g);
                f32x4u m2 = *(const f32x4u*)(mr + 32 + 4*g);
                float m48 = mr[48];
                #pragma unroll
                for (int r = 0; r < 4; ++r) {
                    s[0][r] += m0[r]; s[1][r] += m1[r]; s[2][r] += m2[r];
                }
                s[3][0] = (g == 0) ? s[3][0] + m48 : -1e30f;
                s[3][1] = -1e30f; s[3][2] = -1e30f; s[3][3] = -1e30f;
            }

            float mx = -1e30f;
            #pragma unroll
            for (int kt = 0; kt < 4; ++kt)
                #pragma unroll
                for (int r = 0; r < 4; ++r) mx = fmaxf(mx, s[kt][r]);
            mx = fmaxf(mx, __shfl_xor(mx, 16));
            mx = fmaxf(mx, __shfl_xor(mx, 32));

            float sum = 0.f;
            bf16x4 p[4];   // P^T D-layout == K=16 B-frag: zero-shuffle handoff
            #pragma unroll
            for (int kt = 0; kt < 4; ++kt) {
                float e0 = __expf(s[kt][0] - mx), e1 = __expf(s[kt][1] - mx);
                float e2 = __expf(s[kt][2] - mx), e3 = __expf(s[kt][3] - mx);
                sum += (e0 + e1) + (e2 + e3);
                bf16x4 pk;
                pk[0] = (bf16_t)e0; pk[1] = (bf16_t)e1;
                pk[2] = (bf16_t)e2; pk[3] = (bf16_t)e3;
                p[kt] = pk;
            }
            sum += __shfl_xor(sum, 16);
            sum += __shfl_xor(sum, 32);
            float inv = 1.f / sum;   // uniform across the 4 lanes of each c0 column

            f32x4 oo[2];
            oo[0] = {0.f, 0.f, 0.f, 0.f}; oo[1] = {0.f, 0.f, 0.f, 0.f};
            #pragma unroll
            for (int kt = 0; kt < 4; ++kt) {
                oo[0] = MFMA16(vfr[0][kt], p[kt], oo[0]);
                oo[1] = MFMA16(vfr[1][kt], p[kt], oo[1]);
            }
            int q = 16*qt + c0;
            #pragma unroll
            for (int dt = 0; dt < 2; ++dt) {
                bf16x4 t;
                t[0] = (bf16_t)(oo[dt][0] * inv); t[1] = (bf16_t)(oo[dt][1] * inv);
                t[2] = (bf16_t)(oo[dt][2] * inv); t[3] = (bf16_t)(oo[dt][3] * inv);
                st4(xs, q, (32*h + 16*dt + 4*g) * 2, t);   // att[q][c]
            }
        }
    }

    // prefetch proj weights + bias so they're in flight across the barrier
    bf16x8 pwf[4][2];
    float4 pb0, pb1;
    if (active) {
        #pragma unroll
        for (int ks = 0; ks < 4; ++ks) {
            pwf[ks][0] = ldw<USEB>(pwg, wpb, (32*h + c0) * 128 + 32*ks + 8*g);
            pwf[ks][1] = ldw<USEB>(pwg, wpb, (32*h + 16 + c0) * 128 + 32*ks + 8*g);
        }
        pb0 = *(const float4*)(pbg + 32*h + 4*g);
        pb1 = *(const float4*)(pbg + 32*h + 16 + 4*g);
    }
    __syncthreads();   // b3: att complete

    if (active) {
        // ---- proj GEMM: D[col][tok] = Wp * att^T ----
        f32x4 acc[2][4];
        #pragma unroll
        for (int nt = 0; nt < 2; ++nt)
            #pragma unroll
            for (int mt = 0; mt < 4; ++mt) acc[nt][mt] = {0.f, 0.f, 0.f, 0.f};
        #pragma unroll
        for (int ks = 0; ks < 4; ++ks) {
            #pragma unroll
            for (int mt = 0; mt < 4; ++mt) {
                bf16x8 af = ld8(xs, 16*mt + c0, (32*ks + 8*g) * 2);
                acc[0][mt] = MFMA32(pwf[ks][0], af, acc[0][mt]);
                acc[1][mt] = MFMA32(pwf[ks][1], af, acc[1][mt]);
            }
        }
        float* ob = outg + b * 6272;
        #pragma unroll
        for (int nt = 0; nt < 2; ++nt) {
            float4 pb = nt ? pb1 : pb0;
            #pragma unroll
            for (int mt = 0; mt < 4; ++mt) {
                int tok = 16*mt + c0;
                if (tok < 49) {
                    float4 t;
                    t.x = acc[nt][mt][0] + pb.x;
                    t.y = acc[nt][mt][1] + pb.y;
                    t.z = acc[nt][mt][2] + pb.z;
                    t.w = acc[nt][mt][3] + pb.w;
                    *(float4*)(ob + tok*128 + 32*h + 16*nt + 4*g) = t;
                }
            }
        }
    }
}

extern "C" void kernel_launch(void* const* d_in, const int* in_sizes, int n_in,
                              void* d_out, int out_size, void* d_ws, size_t ws_size,
                              hipStream_t stream) {
    const float* xg  = (const float*)d_in[0];
    const float* mg  = (const float*)d_in[1];
    const float* qwg = (const float*)d_in[2];
    const float* qbg = (const float*)d_in[3];
    const float* pwg = (const float*)d_in[4];
    const float* pbg = (const float*)d_in[5];
    float* outg = (float*)d_out;

    const int B  = in_sizes[0] / (49 * 128);   // 2048
    const int nW = in_sizes[1] / (49 * 49);    // 64
    const int nblk = (B + 1) / 2;

    if (d_ws != nullptr && ws_size >= 131072) {
        bf16_t* wqb = (bf16_t*)d_ws;          // [384][128] bf16
        bf16_t* wpb = wqb + 49152;            // [128][128] bf16
        wconv_kernel<<<64, 256, 0, stream>>>(qwg, pwg, wqb);
        winattn_kernel<1><<<nblk, 512, 0, stream>>>(
            xg, mg, qwg, qbg, pwg, pbg, wqb, wpb, nW, B, outg);
    } else {
        winattn_kernel<0><<<nblk, 512, 0, stream>>>(
            xg, mg, qwg, qbg, pwg, pbg, nullptr, nullptr, nW, B, outg);
    }
}